// Round 3
// baseline (568.808 us; speedup 1.0000x reference)
//
#include <hip/hip_runtime.h>

// ---------------------------------------------------------------------------
// TopoTransform: batched sign-fixed QR (MGS) + per-site channel mix.
//   problem 0: B=32, C=64,  S=784   problem 1: B=32, C=256, S=196
//   out[b][c][s] = sum_k Q[s][c][k] * x[b][k][s],  Q[s] = qr(W[s]) sign-fixed
// MGS yields R[j][j] > 0 directly => Q already sign-fixed.
//
// R3 change: pin occupancy with amdgpu_waves_per_eu(4,4). R2's
// __launch_bounds__(.,4) only set a MINIMUM waves/EU (= register UPPER bound);
// the compiler still targeted 8 waves/EU (LDS allowed 2 blocks/CU) -> 64-VGPR
// budget -> spilled the 64-float `a` tile (533us @ 25% VALUBusy, ~26GB scratch
// traffic). (4,4) pins the target: 128-VGPR budget, tile stays resident.
// ---------------------------------------------------------------------------

static constexpr int BB = 32;  // batch

// -------- transpose: in (R, S) row-major -> out (S, R) row-major ----------
__global__ __launch_bounds__(256) void tkern(const float* __restrict__ in,
                                             float* __restrict__ out,
                                             int R, int S) {
    __shared__ float tile[32][33];
    const int tx = threadIdx.x, ty = threadIdx.y;
    const int s0 = blockIdx.x * 32, r0 = blockIdx.y * 32;
    #pragma unroll
    for (int i = ty; i < 32; i += 8) {
        int r = r0 + i, s = s0 + tx;
        tile[i][tx] = (r < R && s < S) ? in[(size_t)r * S + s] : 0.f;
    }
    __syncthreads();
    #pragma unroll
    for (int i = ty; i < 32; i += 8) {
        int s = s0 + i, r = r0 + tx;
        if (s < S && r < R) out[(size_t)s * R + r] = tile[tx][i];
    }
}

// -------- fused register-resident MGS QR + apply ---------------------------
// Thread grid: RT=16 row-blocks x CT col-blocks (THREADS = 16*CT).
// t: rb = t&15 (16 consecutive lanes per column group -> shfl reductions),
//    cb = t>>4. Thread owns A[rb*TR + i][cb*4 + q], i<TR, q<4, in registers.
template<int C, int CT, int KC>
__global__ __launch_bounds__(16 * CT)
__attribute__((amdgpu_waves_per_eu(4, 4)))
void qr_apply(const float* __restrict__ W, float* __restrict__ XY) {
    constexpr int RT = 16;
    constexpr int TR = C / RT;      // rows per thread
    constexpr int TC = C / CT;      // cols per thread
    static_assert(TC == 4, "col tile must be 4 (float4 paths)");
    constexpr int THREADS = RT * CT;
    constexpr int QSTR = TR + 4;    // padded q stride
    constexpr int XSTR = C + 4;

    const int s  = blockIdx.x;
    const int t  = threadIdx.x;
    const int rb = t & 15;
    const int cb = t >> 4;

    __shared__ float qs[2][RT * QSTR];   // double-buffered q_j
    __shared__ float xs[BB * XSTR];      // X_s staged (B x C)
    __shared__ float qc[KC * C];         // Q chunk [kk][c], xor-swizzled

    // ---- load A tile (float4 rows) ----
    float a[TR][4];
    {
        const float* Wp = W + (size_t)s * C * C + (size_t)(rb * TR) * C + cb * 4;
        #pragma unroll
        for (int i = 0; i < TR; ++i) {
            float4 v = *reinterpret_cast<const float4*>(Wp + (size_t)i * C);
            a[i][0] = v.x; a[i][1] = v.y; a[i][2] = v.z; a[i][3] = v.w;
        }
    }
    // ---- stage X_s into LDS ----
    {
        const float* Xp = XY + (size_t)s * BB * C;
        #pragma unroll
        for (int v = 0; v < (BB * C) / (4 * THREADS); ++v) {
            int idx = 4 * (t + v * THREADS);
            int b = idx / C, k = idx % C;
            float4 x4 = *reinterpret_cast<const float4*>(Xp + idx);
            *reinterpret_cast<float4*>(&xs[b * XSTR + k]) = x4;
        }
    }

    // ---- MGS: one barrier per iteration, reductions via shfl over 16 lanes
    int buf = 0;
    #pragma unroll 1
    for (int j = 0; j < C; ++j) {
        const int cbj = j >> 2, jj = j & 3;
        if (cb == cbj) {
            // static-index copies behind wave-uniform branch (rule #20)
            #pragma unroll
            for (int q = 0; q < 4; ++q) {
                if (q == jj) {
                    float p = 0.f;
                    #pragma unroll
                    for (int i = 0; i < TR; ++i) p += a[i][q] * a[i][q];
                    p += __shfl_xor(p, 1); p += __shfl_xor(p, 2);
                    p += __shfl_xor(p, 4); p += __shfl_xor(p, 8);
                    const float rn = 1.0f / sqrtf(p);
                    #pragma unroll
                    for (int i = 0; i < TR; ++i) a[i][q] *= rn;
                    #pragma unroll
                    for (int i = 0; i < TR; i += 4) {
                        *reinterpret_cast<float4*>(&qs[buf][rb * QSTR + i]) =
                            make_float4(a[i][q], a[i+1][q], a[i+2][q], a[i+3][q]);
                    }
                }
            }
        }
        __syncthreads();
        if (cb * 4 + 3 > j) {   // group-uniform guard: shfl lanes stay converged
            float qv[TR];
            #pragma unroll
            for (int i = 0; i < TR; i += 4) {
                float4 v = *reinterpret_cast<const float4*>(&qs[buf][rb * QSTR + i]);
                qv[i] = v.x; qv[i+1] = v.y; qv[i+2] = v.z; qv[i+3] = v.w;
            }
            #pragma unroll
            for (int q = 0; q < 4; ++q) {
                float p = 0.f;
                #pragma unroll
                for (int i = 0; i < TR; ++i) p += a[i][q] * qv[i];
                p += __shfl_xor(p, 1); p += __shfl_xor(p, 2);
                p += __shfl_xor(p, 4); p += __shfl_xor(p, 8);
                if (cb * 4 + q > j) {
                    #pragma unroll
                    for (int i = 0; i < TR; ++i) a[i][q] -= p * qv[i];
                }
            }
        }
        buf ^= 1;
    }

    // ---- apply: Y[b][c] = sum_k Q[c][k] * X[b][k], Q staged in k-chunks ----
    const int u  = t % (C / 4);   // output c-block (4 cols)
    const int bp = t / (C / 4);   // 0..15 -> b pair
    float acc[2][4] = {{0,0,0,0},{0,0,0,0}};

    #pragma unroll 1
    for (int ch = 0; ch < C / KC; ++ch) {
        __syncthreads();  // prev chunk consumed (and X staged for ch==0)
        if (cb >= (ch * KC) / 4 && cb < ((ch + 1) * KC) / 4) {
            #pragma unroll
            for (int q = 0; q < 4; ++q) {
                const int kk = cb * 4 + q - ch * KC;
                const int swz = (kk & 7) << 2;
                #pragma unroll
                for (int i = 0; i < TR; i += 4) {
                    const int cout = rb * TR + i;
                    *reinterpret_cast<float4*>(&qc[kk * C + (cout ^ swz)]) =
                        make_float4(a[i][q], a[i+1][q], a[i+2][q], a[i+3][q]);
                }
            }
        }
        __syncthreads();
        #pragma unroll
        for (int kk = 0; kk < KC; kk += 4) {
            const int k = ch * KC + kk;
            float4 x0 = *reinterpret_cast<const float4*>(&xs[(2*bp    ) * XSTR + k]);
            float4 x1 = *reinterpret_cast<const float4*>(&xs[(2*bp + 1) * XSTR + k]);
            #pragma unroll
            for (int m = 0; m < 4; ++m) {
                const int swz = ((kk + m) & 7) << 2;
                float4 qv4 = *reinterpret_cast<const float4*>(&qc[(kk + m) * C + ((4 * u) ^ swz)]);
                const float xa = (&x0.x)[m], xb = (&x1.x)[m];
                acc[0][0] += xa * qv4.x; acc[0][1] += xa * qv4.y;
                acc[0][2] += xa * qv4.z; acc[0][3] += xa * qv4.w;
                acc[1][0] += xb * qv4.x; acc[1][1] += xb * qv4.y;
                acc[1][2] += xb * qv4.z; acc[1][3] += xb * qv4.w;
            }
        }
    }
    // ---- write Y in place over X_s (coalesced float4) ----
    {
        float* Yp = XY + (size_t)s * BB * C;
        *reinterpret_cast<float4*>(Yp + (2*bp    ) * C + 4 * u) =
            make_float4(acc[0][0], acc[0][1], acc[0][2], acc[0][3]);
        *reinterpret_cast<float4*>(Yp + (2*bp + 1) * C + 4 * u) =
            make_float4(acc[1][0], acc[1][1], acc[1][2], acc[1][3]);
    }
}

extern "C" void kernel_launch(void* const* d_in, const int* in_sizes, int n_in,
                              void* d_out, int out_size, void* d_ws, size_t ws_size,
                              hipStream_t stream) {
    (void)in_sizes; (void)n_in; (void)out_size; (void)ws_size;
    const float* x0 = (const float*)d_in[0];  // (32, 64, 784)
    const float* x1 = (const float*)d_in[1];  // (32, 256, 196)
    const float* W0 = (const float*)d_in[2];  // (784, 64, 64)
    const float* W1 = (const float*)d_in[3];  // (196, 256, 256)
    float* y0  = (float*)d_out;               // (32, 64, 784) flat
    float* y1  = y0 + 1605632;                // (32, 256, 196) flat
    float* xt0 = (float*)d_ws;                // (784, 32*64)
    float* xt1 = xt0 + 1605632;               // (196, 32*256)

    dim3 tb(32, 8);
    // x (B*C, S) -> xt (S, B*C)
    tkern<<<dim3(25,  64), tb, 0, stream>>>(x0, xt0, 2048, 784);
    tkern<<<dim3(7,  256), tb, 0, stream>>>(x1, xt1, 8192, 196);
    // fused QR + apply (Y overwrites xt in place)
    qr_apply< 64, 16, 64><<<784,  256, 0, stream>>>(W0, xt0);
    qr_apply<256, 64, 16><<<196, 1024, 0, stream>>>(W1, xt1);
    // xt (S, B*C) -> y (B*C, S)
    tkern<<<dim3(64,  25), tb, 0, stream>>>(xt0, y0, 784, 2048);
    tkern<<<dim3(256,  7), tb, 0, stream>>>(xt1, y1, 196, 8192);
}

// Round 4
// 473.486 us; speedup vs baseline: 1.2013x; 1.2013x over previous
//
#include <hip/hip_runtime.h>

// ---------------------------------------------------------------------------
// TopoTransform: batched sign-fixed QR (MGS) + per-site channel mix.
//   problem 0: B=32, C=64,  S=784   problem 1: B=32, C=256, S=196
//   out[b][c][s] = sum_k Q[s][c][k] * x[b][k][s],  Q[s] = qr(W[s]) sign-fixed
// MGS yields R[j][j] > 0 directly => Q already sign-fixed.
//
// R4 change: KC 16 -> 64 for C=256 so LDS/block = 101,376 B > 80 KB.
// Evidence so far: the 64-float register tile spills (WRITE_SIZE 43 MB vs
// 6.4 MB of real output; VALUBusy*dur == no-spill VALU estimate) because the
// allocator targets 8 waves/EU (2 blocks/CU). But grid = 196 blocks < 256
// CUs: a CU can never host 2 blocks, so that target buys nothing. Attributes
// (launch_bounds min-waves, waves_per_eu) failed to move the VGPR budget;
// the LDS footprint feeds computeOccupancy() directly -> >80 KB forces the
// 1-block/CU = 4-waves/EU budget = 128 VGPRs. No arithmetic-order change.
// ---------------------------------------------------------------------------

static constexpr int BB = 32;  // batch

// -------- transpose: in (R, S) row-major -> out (S, R) row-major ----------
__global__ __launch_bounds__(256) void tkern(const float* __restrict__ in,
                                             float* __restrict__ out,
                                             int R, int S) {
    __shared__ float tile[32][33];
    const int tx = threadIdx.x, ty = threadIdx.y;
    const int s0 = blockIdx.x * 32, r0 = blockIdx.y * 32;
    #pragma unroll
    for (int i = ty; i < 32; i += 8) {
        int r = r0 + i, s = s0 + tx;
        tile[i][tx] = (r < R && s < S) ? in[(size_t)r * S + s] : 0.f;
    }
    __syncthreads();
    #pragma unroll
    for (int i = ty; i < 32; i += 8) {
        int s = s0 + i, r = r0 + tx;
        if (s < S && r < R) out[(size_t)s * R + r] = tile[tx][i];
    }
}

// -------- fused register-resident MGS QR + apply ---------------------------
// Thread grid: RT=16 row-blocks x CT col-blocks (THREADS = 16*CT).
// t: rb = t&15 (16 consecutive lanes per column group -> shfl reductions),
//    cb = t>>4. Thread owns A[rb*TR + i][cb*4 + q], i<TR, q<4, in registers.
template<int C, int CT, int KC>
__global__ __launch_bounds__(16 * CT) void qr_apply(const float* __restrict__ W,
                                                    float* __restrict__ XY) {
    constexpr int RT = 16;
    constexpr int TR = C / RT;      // rows per thread
    constexpr int TC = C / CT;      // cols per thread
    static_assert(TC == 4, "col tile must be 4 (float4 paths)");
    constexpr int THREADS = RT * CT;
    constexpr int QSTR = TR + 4;    // padded q stride
    constexpr int XSTR = C + 4;

    const int s  = blockIdx.x;
    const int t  = threadIdx.x;
    const int rb = t & 15;
    const int cb = t >> 4;

    __shared__ float qs[2][RT * QSTR];   // double-buffered q_j
    __shared__ float xs[BB * XSTR];      // X_s staged (B x C)
    __shared__ float qc[KC * C];         // Q chunk [kk][c], xor-swizzled

    // ---- load A tile (float4 rows) ----
    float a[TR][4];
    {
        const float* Wp = W + (size_t)s * C * C + (size_t)(rb * TR) * C + cb * 4;
        #pragma unroll
        for (int i = 0; i < TR; ++i) {
            float4 v = *reinterpret_cast<const float4*>(Wp + (size_t)i * C);
            a[i][0] = v.x; a[i][1] = v.y; a[i][2] = v.z; a[i][3] = v.w;
        }
    }
    // ---- stage X_s into LDS ----
    {
        const float* Xp = XY + (size_t)s * BB * C;
        #pragma unroll
        for (int v = 0; v < (BB * C) / (4 * THREADS); ++v) {
            int idx = 4 * (t + v * THREADS);
            int b = idx / C, k = idx % C;
            float4 x4 = *reinterpret_cast<const float4*>(Xp + idx);
            *reinterpret_cast<float4*>(&xs[b * XSTR + k]) = x4;
        }
    }

    // ---- MGS: one barrier per iteration, reductions via shfl over 16 lanes
    int buf = 0;
    #pragma unroll 1
    for (int j = 0; j < C; ++j) {
        const int cbj = j >> 2, jj = j & 3;
        if (cb == cbj) {
            // static-index copies behind wave-uniform branch (rule #20)
            #pragma unroll
            for (int q = 0; q < 4; ++q) {
                if (q == jj) {
                    float p = 0.f;
                    #pragma unroll
                    for (int i = 0; i < TR; ++i) p += a[i][q] * a[i][q];
                    p += __shfl_xor(p, 1); p += __shfl_xor(p, 2);
                    p += __shfl_xor(p, 4); p += __shfl_xor(p, 8);
                    const float rn = 1.0f / sqrtf(p);
                    #pragma unroll
                    for (int i = 0; i < TR; ++i) a[i][q] *= rn;
                    #pragma unroll
                    for (int i = 0; i < TR; i += 4) {
                        *reinterpret_cast<float4*>(&qs[buf][rb * QSTR + i]) =
                            make_float4(a[i][q], a[i+1][q], a[i+2][q], a[i+3][q]);
                    }
                }
            }
        }
        __syncthreads();
        if (cb * 4 + 3 > j) {   // group-uniform guard: shfl lanes stay converged
            float qv[TR];
            #pragma unroll
            for (int i = 0; i < TR; i += 4) {
                float4 v = *reinterpret_cast<const float4*>(&qs[buf][rb * QSTR + i]);
                qv[i] = v.x; qv[i+1] = v.y; qv[i+2] = v.z; qv[i+3] = v.w;
            }
            #pragma unroll
            for (int q = 0; q < 4; ++q) {
                float p = 0.f;
                #pragma unroll
                for (int i = 0; i < TR; ++i) p += a[i][q] * qv[i];
                p += __shfl_xor(p, 1); p += __shfl_xor(p, 2);
                p += __shfl_xor(p, 4); p += __shfl_xor(p, 8);
                if (cb * 4 + q > j) {
                    #pragma unroll
                    for (int i = 0; i < TR; ++i) a[i][q] -= p * qv[i];
                }
            }
        }
        buf ^= 1;
    }

    // ---- apply: Y[b][c] = sum_k Q[c][k] * X[b][k], Q staged in k-chunks ----
    const int u  = t % (C / 4);   // output c-block (4 cols)
    const int bp = t / (C / 4);   // 0..15 -> b pair
    float acc[2][4] = {{0,0,0,0},{0,0,0,0}};

    #pragma unroll 1
    for (int ch = 0; ch < C / KC; ++ch) {
        __syncthreads();  // prev chunk consumed (and X staged for ch==0)
        if (cb >= (ch * KC) / 4 && cb < ((ch + 1) * KC) / 4) {
            #pragma unroll
            for (int q = 0; q < 4; ++q) {
                const int kk = cb * 4 + q - ch * KC;
                const int swz = (kk & 7) << 2;
                #pragma unroll
                for (int i = 0; i < TR; i += 4) {
                    const int cout = rb * TR + i;
                    *reinterpret_cast<float4*>(&qc[kk * C + (cout ^ swz)]) =
                        make_float4(a[i][q], a[i+1][q], a[i+2][q], a[i+3][q]);
                }
            }
        }
        __syncthreads();
        #pragma unroll
        for (int kk = 0; kk < KC; kk += 4) {
            const int k = ch * KC + kk;
            float4 x0 = *reinterpret_cast<const float4*>(&xs[(2*bp    ) * XSTR + k]);
            float4 x1 = *reinterpret_cast<const float4*>(&xs[(2*bp + 1) * XSTR + k]);
            #pragma unroll
            for (int m = 0; m < 4; ++m) {
                const int swz = ((kk + m) & 7) << 2;
                float4 qv4 = *reinterpret_cast<const float4*>(&qc[(kk + m) * C + ((4 * u) ^ swz)]);
                const float xa = (&x0.x)[m], xb = (&x1.x)[m];
                acc[0][0] += xa * qv4.x; acc[0][1] += xa * qv4.y;
                acc[0][2] += xa * qv4.z; acc[0][3] += xa * qv4.w;
                acc[1][0] += xb * qv4.x; acc[1][1] += xb * qv4.y;
                acc[1][2] += xb * qv4.z; acc[1][3] += xb * qv4.w;
            }
        }
    }
    // ---- write Y in place over X_s (coalesced float4) ----
    {
        float* Yp = XY + (size_t)s * BB * C;
        *reinterpret_cast<float4*>(Yp + (2*bp    ) * C + 4 * u) =
            make_float4(acc[0][0], acc[0][1], acc[0][2], acc[0][3]);
        *reinterpret_cast<float4*>(Yp + (2*bp + 1) * C + 4 * u) =
            make_float4(acc[1][0], acc[1][1], acc[1][2], acc[1][3]);
    }
}

extern "C" void kernel_launch(void* const* d_in, const int* in_sizes, int n_in,
                              void* d_out, int out_size, void* d_ws, size_t ws_size,
                              hipStream_t stream) {
    (void)in_sizes; (void)n_in; (void)out_size; (void)ws_size;
    const float* x0 = (const float*)d_in[0];  // (32, 64, 784)
    const float* x1 = (const float*)d_in[1];  // (32, 256, 196)
    const float* W0 = (const float*)d_in[2];  // (784, 64, 64)
    const float* W1 = (const float*)d_in[3];  // (196, 256, 256)
    float* y0  = (float*)d_out;               // (32, 64, 784) flat
    float* y1  = y0 + 1605632;                // (32, 256, 196) flat
    float* xt0 = (float*)d_ws;                // (784, 32*64)
    float* xt1 = xt0 + 1605632;               // (196, 32*256)

    dim3 tb(32, 8);
    // x (B*C, S) -> xt (S, B*C)
    tkern<<<dim3(25,  64), tb, 0, stream>>>(x0, xt0, 2048, 784);
    tkern<<<dim3(7,  256), tb, 0, stream>>>(x1, xt1, 8192, 196);
    // fused QR + apply (Y overwrites xt in place)
    qr_apply< 64, 16, 64><<<784,  256, 0, stream>>>(W0, xt0);
    qr_apply<256, 64, 64><<<196, 1024, 0, stream>>>(W1, xt1);  // KC=64: LDS 101,376 B -> 1 block/CU -> 128-VGPR budget
    // xt (S, B*C) -> y (B*C, S)
    tkern<<<dim3(64,  25), tb, 0, stream>>>(xt0, y0, 784, 2048);
    tkern<<<dim3(256,  7), tb, 0, stream>>>(xt1, y1, 196, 8192);
}

// Round 5
// 348.500 us; speedup vs baseline: 1.6322x; 1.3586x over previous
//
#include <hip/hip_runtime.h>

// ---------------------------------------------------------------------------
// TopoTransform: batched sign-fixed QR (MGS) + per-site channel mix.
//   problem 0: B=32, C=64,  S=784   problem 1: B=32, C=256, S=196
//   out[b][c][s] = sum_k Q[s][c][k] * x[b][k][s],  Q[s] = qr(W[s]) sign-fixed
// MGS yields R[j][j] > 0 directly => Q already sign-fixed.
//
// R5 changes:
//  (a) amdgpu_num_vgpr(128) on the C=256 wrapper: R1-R4 show the backend
//      budgets for 2 workgroups/CU (1024thr -> 8 waves/EU -> 64 VGPR) no
//      matter what occupancy hints/LDS say; the 64-float tile spills
//      (WRITE_SIZE 45.5MB vs 6.4MB legit). num_vgpr sets allocation directly.
//  (b) DPP row_ror rotate-reduce replaces __shfl_xor: reductions move from
//      the single per-CU DS pipe (~150us of ds_bpermute load) to the VALU.
//      cb-groups are aligned 16-lane DPP rows; guards are row-uniform.
//  (c) per-q guard now covers the dot+reduce too (halves wasted dot work).
// ---------------------------------------------------------------------------

static constexpr int BB = 32;  // batch

// -------- DPP 16-lane all-reduce (sum) on the VALU pipe --------------------
template<int CTRL>
__device__ __forceinline__ float dpp_add(float x) {
    int y = __builtin_amdgcn_update_dpp(0, __float_as_int(x), CTRL, 0xF, 0xF, false);
    return x + __int_as_float(y);
}
__device__ __forceinline__ float rowred16(float p) {
    p = dpp_add<0x128>(p);  // row_ror:8
    p = dpp_add<0x124>(p);  // row_ror:4
    p = dpp_add<0x122>(p);  // row_ror:2
    p = dpp_add<0x121>(p);  // row_ror:1
    return p;               // all 16 lanes of the row hold the sum
}

// -------- transpose: in (R, S) row-major -> out (S, R) row-major ----------
__global__ __launch_bounds__(256) void tkern(const float* __restrict__ in,
                                             float* __restrict__ out,
                                             int R, int S) {
    __shared__ float tile[32][33];
    const int tx = threadIdx.x, ty = threadIdx.y;
    const int s0 = blockIdx.x * 32, r0 = blockIdx.y * 32;
    #pragma unroll
    for (int i = ty; i < 32; i += 8) {
        int r = r0 + i, s = s0 + tx;
        tile[i][tx] = (r < R && s < S) ? in[(size_t)r * S + s] : 0.f;
    }
    __syncthreads();
    #pragma unroll
    for (int i = ty; i < 32; i += 8) {
        int s = s0 + i, r = r0 + tx;
        if (s < S && r < R) out[(size_t)s * R + r] = tile[tx][i];
    }
}

// -------- fused register-resident MGS QR + apply (device body) -------------
// Thread grid: RT=16 row-blocks x CT col-blocks (THREADS = 16*CT).
// t: rb = t&15 (aligned 16-lane DPP row per cb group), cb = t>>4.
// Thread owns A[rb*TR + i][cb*4 + q], i<TR, q<4, in registers.
template<int C, int CT, int KC>
__device__ __forceinline__ void qr_body(const float* __restrict__ W,
                                        float* __restrict__ XY) {
    constexpr int RT = 16;
    constexpr int TR = C / RT;      // rows per thread
    constexpr int TC = C / CT;      // cols per thread
    static_assert(TC == 4, "col tile must be 4 (float4 paths)");
    constexpr int THREADS = RT * CT;
    constexpr int QSTR = TR + 4;    // padded q stride
    constexpr int XSTR = C + 4;

    const int s  = blockIdx.x;
    const int t  = threadIdx.x;
    const int rb = t & 15;
    const int cb = t >> 4;

    __shared__ float qs[2][RT * QSTR];   // double-buffered q_j
    __shared__ float xs[BB * XSTR];      // X_s staged (B x C)
    __shared__ float qc[KC * C];         // Q chunk [kk][c], xor-swizzled

    // ---- load A tile (float4 rows) ----
    float a[TR][4];
    {
        const float* Wp = W + (size_t)s * C * C + (size_t)(rb * TR) * C + cb * 4;
        #pragma unroll
        for (int i = 0; i < TR; ++i) {
            float4 v = *reinterpret_cast<const float4*>(Wp + (size_t)i * C);
            a[i][0] = v.x; a[i][1] = v.y; a[i][2] = v.z; a[i][3] = v.w;
        }
    }
    // ---- stage X_s into LDS ----
    {
        const float* Xp = XY + (size_t)s * BB * C;
        #pragma unroll
        for (int v = 0; v < (BB * C) / (4 * THREADS); ++v) {
            int idx = 4 * (t + v * THREADS);
            int b = idx / C, k = idx % C;
            float4 x4 = *reinterpret_cast<const float4*>(Xp + idx);
            *reinterpret_cast<float4*>(&xs[b * XSTR + k]) = x4;
        }
    }

    // ---- MGS: one barrier per iteration, DPP reductions on the VALU ------
    int buf = 0;
    #pragma unroll 1
    for (int j = 0; j < C; ++j) {
        const int cbj = j >> 2, jj = j & 3;
        if (cb == cbj) {
            // static-index copies behind row-uniform branch (rule #20)
            #pragma unroll
            for (int q = 0; q < 4; ++q) {
                if (q == jj) {
                    float p = 0.f;
                    #pragma unroll
                    for (int i = 0; i < TR; ++i) p += a[i][q] * a[i][q];
                    p = rowred16(p);
                    const float rn = 1.0f / sqrtf(p);
                    #pragma unroll
                    for (int i = 0; i < TR; ++i) a[i][q] *= rn;
                    #pragma unroll
                    for (int i = 0; i < TR; i += 4) {
                        *reinterpret_cast<float4*>(&qs[buf][rb * QSTR + i]) =
                            make_float4(a[i][q], a[i+1][q], a[i+2][q], a[i+3][q]);
                    }
                }
            }
        }
        __syncthreads();
        if (cb * 4 + 3 > j) {   // row-uniform guard: DPP rows stay converged
            float qv[TR];
            #pragma unroll
            for (int i = 0; i < TR; i += 4) {
                float4 v = *reinterpret_cast<const float4*>(&qs[buf][rb * QSTR + i]);
                qv[i] = v.x; qv[i+1] = v.y; qv[i+2] = v.z; qv[i+3] = v.w;
            }
            #pragma unroll
            for (int q = 0; q < 4; ++q) {
                if (cb * 4 + q > j) {   // row-uniform per-q guard
                    float p = 0.f;
                    #pragma unroll
                    for (int i = 0; i < TR; ++i) p += a[i][q] * qv[i];
                    p = rowred16(p);
                    #pragma unroll
                    for (int i = 0; i < TR; ++i) a[i][q] -= p * qv[i];
                }
            }
        }
        buf ^= 1;
    }

    // ---- apply: Y[b][c] = sum_k Q[c][k] * X[b][k], Q staged in k-chunks ----
    const int u  = t % (C / 4);   // output c-block (4 cols)
    const int bp = t / (C / 4);   // b-pair index
    float acc[2][4] = {{0,0,0,0},{0,0,0,0}};

    #pragma unroll 1
    for (int ch = 0; ch < C / KC; ++ch) {
        __syncthreads();  // prev chunk consumed (and X staged for ch==0)
        if (cb >= (ch * KC) / 4 && cb < ((ch + 1) * KC) / 4) {
            #pragma unroll
            for (int q = 0; q < 4; ++q) {
                const int kk = cb * 4 + q - ch * KC;
                const int swz = (kk & 7) << 2;
                #pragma unroll
                for (int i = 0; i < TR; i += 4) {
                    const int cout = rb * TR + i;
                    *reinterpret_cast<float4*>(&qc[kk * C + (cout ^ swz)]) =
                        make_float4(a[i][q], a[i+1][q], a[i+2][q], a[i+3][q]);
                }
            }
        }
        __syncthreads();
        #pragma unroll
        for (int kk = 0; kk < KC; kk += 4) {
            const int k = ch * KC + kk;
            float4 x0 = *reinterpret_cast<const float4*>(&xs[(2*bp    ) * XSTR + k]);
            float4 x1 = *reinterpret_cast<const float4*>(&xs[(2*bp + 1) * XSTR + k]);
            #pragma unroll
            for (int m = 0; m < 4; ++m) {
                const int swz = ((kk + m) & 7) << 2;
                float4 qv4 = *reinterpret_cast<const float4*>(&qc[(kk + m) * C + ((4 * u) ^ swz)]);
                const float xa = (&x0.x)[m], xb = (&x1.x)[m];
                acc[0][0] += xa * qv4.x; acc[0][1] += xa * qv4.y;
                acc[0][2] += xa * qv4.z; acc[0][3] += xa * qv4.w;
                acc[1][0] += xb * qv4.x; acc[1][1] += xb * qv4.y;
                acc[1][2] += xb * qv4.z; acc[1][3] += xb * qv4.w;
            }
        }
    }
    // ---- write Y in place over X_s (coalesced float4) ----
    {
        float* Yp = XY + (size_t)s * BB * C;
        *reinterpret_cast<float4*>(Yp + (2*bp    ) * C + 4 * u) =
            make_float4(acc[0][0], acc[0][1], acc[0][2], acc[0][3]);
        *reinterpret_cast<float4*>(Yp + (2*bp + 1) * C + 4 * u) =
            make_float4(acc[1][0], acc[1][1], acc[1][2], acc[1][3]);
    }
}

// Thin wrappers: attributes differ per instantiation.
__global__ __launch_bounds__(256) void qr64(const float* __restrict__ W,
                                            float* __restrict__ XY) {
    qr_body<64, 16, 64>(W, XY);
}

__global__ __launch_bounds__(1024)
__attribute__((amdgpu_num_vgpr(128), amdgpu_waves_per_eu(4, 4)))
void qr256(const float* __restrict__ W, float* __restrict__ XY) {
    qr_body<256, 64, 64>(W, XY);
}

extern "C" void kernel_launch(void* const* d_in, const int* in_sizes, int n_in,
                              void* d_out, int out_size, void* d_ws, size_t ws_size,
                              hipStream_t stream) {
    (void)in_sizes; (void)n_in; (void)out_size; (void)ws_size;
    const float* x0 = (const float*)d_in[0];  // (32, 64, 784)
    const float* x1 = (const float*)d_in[1];  // (32, 256, 196)
    const float* W0 = (const float*)d_in[2];  // (784, 64, 64)
    const float* W1 = (const float*)d_in[3];  // (196, 256, 256)
    float* y0  = (float*)d_out;               // (32, 64, 784) flat
    float* y1  = y0 + 1605632;                // (32, 256, 196) flat
    float* xt0 = (float*)d_ws;                // (784, 32*64)
    float* xt1 = xt0 + 1605632;               // (196, 32*256)

    dim3 tb(32, 8);
    // x (B*C, S) -> xt (S, B*C)
    tkern<<<dim3(25,  64), tb, 0, stream>>>(x0, xt0, 2048, 784);
    tkern<<<dim3(7,  256), tb, 0, stream>>>(x1, xt1, 8192, 196);
    // fused QR + apply (Y overwrites xt in place)
    qr64 <<<784,  256, 0, stream>>>(W0, xt0);
    qr256<<<196, 1024, 0, stream>>>(W1, xt1);
    // xt (S, B*C) -> y (B*C, S)
    tkern<<<dim3(64,  25), tb, 0, stream>>>(xt0, y0, 784, 2048);
    tkern<<<dim3(256,  7), tb, 0, stream>>>(xt1, y1, 196, 8192);
}

// Round 6
// 324.577 us; speedup vs baseline: 1.7525x; 1.0737x over previous
//
#include <hip/hip_runtime.h>

// ---------------------------------------------------------------------------
// TopoTransform: batched sign-fixed QR (MGS) + per-site channel mix.
//   problem 0: B=32, C=64,  S=784   problem 1: B=32, C=256, S=196
//   out[b][c][s] = sum_k Q[s][c][k] * x[b][k][s],  Q[s] = qr(W[s]) sign-fixed
// MGS yields R[j][j] > 0 directly => Q already sign-fixed.
//
// R6: C=256 rebuilt as LEFT-LOOKING 2-panel MGS sized for the 64-VGPR budget
// (R1-R5 evidence: 1024-thr workgroups always get 64 VGPRs; the 64-float tile
// spilled -> 45.5MB WRITE_SIZE). Panel of 128 cols in regs (32 f/thread),
// finished q's in LDS (qpan, 1KB/col slot -> race-free 1 barrier/step),
// barrier-free cross-pass for panel 1, apply fused as rank-1 (j-ascending =
// bit-identical to R5's k-ascending sum). All fp trees match R5 exactly.
// ---------------------------------------------------------------------------

static constexpr int BB = 32;  // batch

// -------- DPP 16-lane all-reduce (sum) on the VALU pipe --------------------
template<int CTRL>
__device__ __forceinline__ float dpp_add(float x) {
    int y = __builtin_amdgcn_update_dpp(0, __float_as_int(x), CTRL, 0xF, 0xF, false);
    return x + __int_as_float(y);
}
__device__ __forceinline__ float rowred16(float p) {
    p = dpp_add<0x128>(p);  // row_ror:8
    p = dpp_add<0x124>(p);  // row_ror:4
    p = dpp_add<0x122>(p);  // row_ror:2
    p = dpp_add<0x121>(p);  // row_ror:1
    return p;               // all 16 lanes of the row hold the sum
}

// -------- transpose: in (R, S) row-major -> out (S, R) row-major ----------
__global__ __launch_bounds__(256) void tkern(const float* __restrict__ in,
                                             float* __restrict__ out,
                                             int R, int S) {
    __shared__ float tile[32][33];
    const int tx = threadIdx.x, ty = threadIdx.y;
    const int s0 = blockIdx.x * 32, r0 = blockIdx.y * 32;
    #pragma unroll
    for (int i = ty; i < 32; i += 8) {
        int r = r0 + i, s = s0 + tx;
        tile[i][tx] = (r < R && s < S) ? in[(size_t)r * S + s] : 0.f;
    }
    __syncthreads();
    #pragma unroll
    for (int i = ty; i < 32; i += 8) {
        int s = s0 + i, r = r0 + tx;
        if (s < S && r < R) out[(size_t)s * R + r] = tile[tx][i];
    }
}

// ===========================================================================
// C=64 path: unchanged from R5 (register-resident MGS + chunked apply).
// ===========================================================================
template<int C, int CT, int KC>
__device__ __forceinline__ void qr_body(const float* __restrict__ W,
                                        float* __restrict__ XY) {
    constexpr int RT = 16;
    constexpr int TR = C / RT;
    constexpr int THREADS = RT * CT;
    constexpr int QSTR = TR + 4;
    constexpr int XSTR = C + 4;

    const int s  = blockIdx.x;
    const int t  = threadIdx.x;
    const int rb = t & 15;
    const int cb = t >> 4;

    __shared__ float qs[2][RT * QSTR];
    __shared__ float xs[BB * XSTR];
    __shared__ float qc[KC * C];

    float a[TR][4];
    {
        const float* Wp = W + (size_t)s * C * C + (size_t)(rb * TR) * C + cb * 4;
        #pragma unroll
        for (int i = 0; i < TR; ++i) {
            float4 v = *reinterpret_cast<const float4*>(Wp + (size_t)i * C);
            a[i][0] = v.x; a[i][1] = v.y; a[i][2] = v.z; a[i][3] = v.w;
        }
    }
    {
        const float* Xp = XY + (size_t)s * BB * C;
        #pragma unroll
        for (int v = 0; v < (BB * C) / (4 * THREADS); ++v) {
            int idx = 4 * (t + v * THREADS);
            int b = idx / C, k = idx % C;
            float4 x4 = *reinterpret_cast<const float4*>(Xp + idx);
            *reinterpret_cast<float4*>(&xs[b * XSTR + k]) = x4;
        }
    }

    int buf = 0;
    #pragma unroll 1
    for (int j = 0; j < C; ++j) {
        const int cbj = j >> 2, jj = j & 3;
        if (cb == cbj) {
            #pragma unroll
            for (int q = 0; q < 4; ++q) {
                if (q == jj) {
                    float p = 0.f;
                    #pragma unroll
                    for (int i = 0; i < TR; ++i) p += a[i][q] * a[i][q];
                    p = rowred16(p);
                    const float rn = 1.0f / sqrtf(p);
                    #pragma unroll
                    for (int i = 0; i < TR; ++i) a[i][q] *= rn;
                    #pragma unroll
                    for (int i = 0; i < TR; i += 4) {
                        *reinterpret_cast<float4*>(&qs[buf][rb * QSTR + i]) =
                            make_float4(a[i][q], a[i+1][q], a[i+2][q], a[i+3][q]);
                    }
                }
            }
        }
        __syncthreads();
        if (cb * 4 + 3 > j) {
            float qv[TR];
            #pragma unroll
            for (int i = 0; i < TR; i += 4) {
                float4 v = *reinterpret_cast<const float4*>(&qs[buf][rb * QSTR + i]);
                qv[i] = v.x; qv[i+1] = v.y; qv[i+2] = v.z; qv[i+3] = v.w;
            }
            #pragma unroll
            for (int q = 0; q < 4; ++q) {
                if (cb * 4 + q > j) {
                    float p = 0.f;
                    #pragma unroll
                    for (int i = 0; i < TR; ++i) p += a[i][q] * qv[i];
                    p = rowred16(p);
                    #pragma unroll
                    for (int i = 0; i < TR; ++i) a[i][q] -= p * qv[i];
                }
            }
        }
        buf ^= 1;
    }

    const int u  = t % (C / 4);
    const int bp = t / (C / 4);
    float acc[2][4] = {{0,0,0,0},{0,0,0,0}};

    #pragma unroll 1
    for (int ch = 0; ch < C / KC; ++ch) {
        __syncthreads();
        if (cb >= (ch * KC) / 4 && cb < ((ch + 1) * KC) / 4) {
            #pragma unroll
            for (int q = 0; q < 4; ++q) {
                const int kk = cb * 4 + q - ch * KC;
                const int swz = (kk & 7) << 2;
                #pragma unroll
                for (int i = 0; i < TR; i += 4) {
                    const int cout = rb * TR + i;
                    *reinterpret_cast<float4*>(&qc[kk * C + (cout ^ swz)]) =
                        make_float4(a[i][q], a[i+1][q], a[i+2][q], a[i+3][q]);
                }
            }
        }
        __syncthreads();
        #pragma unroll
        for (int kk = 0; kk < KC; kk += 4) {
            const int k = ch * KC + kk;
            float4 x0 = *reinterpret_cast<const float4*>(&xs[(2*bp    ) * XSTR + k]);
            float4 x1 = *reinterpret_cast<const float4*>(&xs[(2*bp + 1) * XSTR + k]);
            #pragma unroll
            for (int m = 0; m < 4; ++m) {
                const int swz = ((kk + m) & 7) << 2;
                float4 qv4 = *reinterpret_cast<const float4*>(&qc[(kk + m) * C + ((4 * u) ^ swz)]);
                const float xa = (&x0.x)[m], xb = (&x1.x)[m];
                acc[0][0] += xa * qv4.x; acc[0][1] += xa * qv4.y;
                acc[0][2] += xa * qv4.z; acc[0][3] += xa * qv4.w;
                acc[1][0] += xb * qv4.x; acc[1][1] += xb * qv4.y;
                acc[1][2] += xb * qv4.z; acc[1][3] += xb * qv4.w;
            }
        }
    }
    {
        float* Yp = XY + (size_t)s * BB * C;
        *reinterpret_cast<float4*>(Yp + (2*bp    ) * C + 4 * u) =
            make_float4(acc[0][0], acc[0][1], acc[0][2], acc[0][3]);
        *reinterpret_cast<float4*>(Yp + (2*bp + 1) * C + 4 * u) =
            make_float4(acc[1][0], acc[1][1], acc[1][2], acc[1][3]);
    }
}

__global__ __launch_bounds__(256) void qr64(const float* __restrict__ W,
                                            float* __restrict__ XY) {
    qr_body<64, 16, 64>(W, XY);
}

// ===========================================================================
// C=256 left-looking 2-panel MGS, 1024 threads, <=~55 VGPR by design.
//   rb = t&15: lane's 16 rows = rb*16..rb*16+15 (same as R5)
//   cb = t>>4: group owns panel cols {2cb, 2cb+1}
//   qpan[j]: 1KB slot, permuted layout: row r=4g+e of col j at j*256+g*64+rb*4+e
//   Y mapping: u=t&63 -> c=4u..4u+3; v=t>>6 -> b=2v,2v+1
// ===========================================================================
__device__ __forceinline__ void panel_mgs(float (&a)[2][16], float (&y0)[4],
                                          float (&y1)[4], float* qpan,
                                          const float* xsb,
                                          int rb, int cb, int u, int v) {
    #pragma unroll 1
    for (int j = 0; j < 128; ++j) {
        if (cb == (j >> 1)) {
            #pragma unroll
            for (int s2 = 0; s2 < 2; ++s2) {
                if (s2 == (j & 1)) {   // static index behind uniform branch
                    float p = 0.f;
                    #pragma unroll
                    for (int i = 0; i < 16; ++i) p += a[s2][i] * a[s2][i];
                    p = rowred16(p);
                    const float rn = 1.0f / sqrtf(p);
                    #pragma unroll
                    for (int i = 0; i < 16; ++i) a[s2][i] *= rn;
                    #pragma unroll
                    for (int g = 0; g < 4; ++g) {
                        *reinterpret_cast<float4*>(&qpan[j*256 + g*64 + rb*4]) =
                            make_float4(a[s2][4*g], a[s2][4*g+1],
                                        a[s2][4*g+2], a[s2][4*g+3]);
                    }
                }
            }
        }
        __syncthreads();
        const bool act1 = (2*cb + 1 > j);
        const bool act0 = (2*cb > j);
        if (act1) {   // row-uniform guard: DPP rows stay converged
            float p0 = 0.f, p1 = 0.f;
            #pragma unroll
            for (int g = 0; g < 4; ++g) {
                float4 q4 = *reinterpret_cast<const float4*>(&qpan[j*256 + g*64 + rb*4]);
                p0 += a[0][4*g  ] * q4.x; p1 += a[1][4*g  ] * q4.x;
                p0 += a[0][4*g+1] * q4.y; p1 += a[1][4*g+1] * q4.y;
                p0 += a[0][4*g+2] * q4.z; p1 += a[1][4*g+2] * q4.z;
                p0 += a[0][4*g+3] * q4.w; p1 += a[1][4*g+3] * q4.w;
            }
            p0 = rowred16(p0); p1 = rowred16(p1);
            #pragma unroll
            for (int g = 0; g < 4; ++g) {
                float4 q4 = *reinterpret_cast<const float4*>(&qpan[j*256 + g*64 + rb*4]);
                if (act0) {
                    a[0][4*g  ] -= p0 * q4.x; a[0][4*g+1] -= p0 * q4.y;
                    a[0][4*g+2] -= p0 * q4.z; a[0][4*g+3] -= p0 * q4.w;
                }
                a[1][4*g  ] -= p1 * q4.x; a[1][4*g+1] -= p1 * q4.y;
                a[1][4*g+2] -= p1 * q4.z; a[1][4*g+3] -= p1 * q4.w;
            }
        }
        {   // fused rank-1 apply: y += x[b,j] * q_j[c]   (j ascending)
            float4 q4 = *reinterpret_cast<const float4*>(
                &qpan[j*256 + (u&3)*64 + (u>>2)*4]);
            const float xa = xsb[j*33 + 2*v];
            const float xb = xsb[j*33 + 2*v + 1];
            y0[0] += xa*q4.x; y0[1] += xa*q4.y; y0[2] += xa*q4.z; y0[3] += xa*q4.w;
            y1[0] += xb*q4.x; y1[1] += xb*q4.y; y1[2] += xb*q4.z; y1[3] += xb*q4.w;
        }
    }
}

__global__ __launch_bounds__(1024) void qr256ll(const float* __restrict__ W,
                                                float* __restrict__ XY) {
    __shared__ float qpan[128 * 256];   // 128 KiB: finished q's, 1KB/col slot
    __shared__ float xsb[128 * 33];     // 16.5 KiB: X panel [col][b], pad 33

    const int s  = blockIdx.x;
    const int t  = threadIdx.x;
    const int rb = t & 15;
    const int cb = t >> 4;
    const int u  = t & 63;
    const int v  = t >> 6;

    const float* Wp = W + (size_t)s * 65536;
    float* Xp = XY + (size_t)s * 8192;

    float a[2][16];
    float y0[4] = {0,0,0,0};
    float y1[4] = {0,0,0,0};

    // ---- panel 0: load W cols [0,128) + stage X cols [0,128) ----
    #pragma unroll
    for (int i = 0; i < 16; ++i) {
        float2 w2 = *reinterpret_cast<const float2*>(
            Wp + (size_t)(rb*16 + i) * 256 + 2*cb);
        a[0][i] = w2.x; a[1][i] = w2.y;
    }
    {
        const int tj = t & 127, tb = t >> 7;
        #pragma unroll
        for (int d = 0; d < 4; ++d)
            xsb[tj*33 + 4*tb + d] = Xp[(4*tb + d)*256 + tj];
    }
    __syncthreads();

    panel_mgs(a, y0, y1, qpan, xsb, rb, cb, u, v);

    // ---- glue: reload regs with W cols [128,256), restage X, cross-pass ----
    __syncthreads();   // panel-0 consumers done before xsb is overwritten
    #pragma unroll
    for (int i = 0; i < 16; ++i) {
        float2 w2 = *reinterpret_cast<const float2*>(
            Wp + (size_t)(rb*16 + i) * 256 + 128 + 2*cb);
        a[0][i] = w2.x; a[1][i] = w2.y;
    }
    {
        const int tj = t & 127, tb = t >> 7;
        #pragma unroll
        for (int d = 0; d < 4; ++d)
            xsb[tj*33 + 4*tb + d] = Xp[(4*tb + d)*256 + 128 + tj];
    }
    // cross-pass: orthogonalize both register cols vs Q0 (barrier-free;
    // qpan is read-only here, xsb writes above touch a disjoint region)
    #pragma unroll 1
    for (int k = 0; k < 128; ++k) {
        float p0 = 0.f, p1 = 0.f;
        #pragma unroll
        for (int g = 0; g < 4; ++g) {
            float4 q4 = *reinterpret_cast<const float4*>(&qpan[k*256 + g*64 + rb*4]);
            p0 += a[0][4*g  ] * q4.x; p1 += a[1][4*g  ] * q4.x;
            p0 += a[0][4*g+1] * q4.y; p1 += a[1][4*g+1] * q4.y;
            p0 += a[0][4*g+2] * q4.z; p1 += a[1][4*g+2] * q4.z;
            p0 += a[0][4*g+3] * q4.w; p1 += a[1][4*g+3] * q4.w;
        }
        p0 = rowred16(p0); p1 = rowred16(p1);
        #pragma unroll
        for (int g = 0; g < 4; ++g) {
            float4 q4 = *reinterpret_cast<const float4*>(&qpan[k*256 + g*64 + rb*4]);
            a[0][4*g  ] -= p0 * q4.x; a[0][4*g+1] -= p0 * q4.y;
            a[0][4*g+2] -= p0 * q4.z; a[0][4*g+3] -= p0 * q4.w;
            a[1][4*g  ] -= p1 * q4.x; a[1][4*g+1] -= p1 * q4.y;
            a[1][4*g+2] -= p1 * q4.z; a[1][4*g+3] -= p1 * q4.w;
        }
    }
    __syncthreads();   // xsb staged + cross-pass complete everywhere

    // ---- panel 1 (qpan slots reused; Q0 no longer needed) ----
    panel_mgs(a, y0, y1, qpan, xsb, rb, cb, u, v);

    // ---- write Y in place over X (coalesced float4) ----
    *reinterpret_cast<float4*>(Xp + (size_t)(2*v    )*256 + 4*u) =
        make_float4(y0[0], y0[1], y0[2], y0[3]);
    *reinterpret_cast<float4*>(Xp + (size_t)(2*v + 1)*256 + 4*u) =
        make_float4(y1[0], y1[1], y1[2], y1[3]);
}

extern "C" void kernel_launch(void* const* d_in, const int* in_sizes, int n_in,
                              void* d_out, int out_size, void* d_ws, size_t ws_size,
                              hipStream_t stream) {
    (void)in_sizes; (void)n_in; (void)out_size; (void)ws_size;
    const float* x0 = (const float*)d_in[0];  // (32, 64, 784)
    const float* x1 = (const float*)d_in[1];  // (32, 256, 196)
    const float* W0 = (const float*)d_in[2];  // (784, 64, 64)
    const float* W1 = (const float*)d_in[3];  // (196, 256, 256)
    float* y0  = (float*)d_out;               // (32, 64, 784) flat
    float* y1  = y0 + 1605632;                // (32, 256, 196) flat
    float* xt0 = (float*)d_ws;                // (784, 32*64)
    float* xt1 = xt0 + 1605632;               // (196, 32*256)

    dim3 tb(32, 8);
    // x (B*C, S) -> xt (S, B*C)
    tkern<<<dim3(25,  64), tb, 0, stream>>>(x0, xt0, 2048, 784);
    tkern<<<dim3(7,  256), tb, 0, stream>>>(x1, xt1, 8192, 196);
    // fused QR + apply (Y overwrites xt in place)
    qr64   <<<784,  256, 0, stream>>>(W0, xt0);
    qr256ll<<<196, 1024, 0, stream>>>(W1, xt1);
    // xt (S, B*C) -> y (B*C, S)
    tkern<<<dim3(64,  25), tb, 0, stream>>>(xt0, y0, 784, 2048);
    tkern<<<dim3(256,  7), tb, 0, stream>>>(xt1, y1, 196, 8192);
}

// Round 7
// 324.163 us; speedup vs baseline: 1.7547x; 1.0013x over previous
//
#include <hip/hip_runtime.h>

// ---------------------------------------------------------------------------
// TopoTransform: batched sign-fixed QR (MGS) + per-site channel mix.
//   problem 0: B=32, C=64,  S=784   problem 1: B=32, C=256, S=196
//   out[b][c][s] = sum_k Q[s][c][k] * x[b][k][s],  Q[s] = qr(W[s]) sign-fixed
// MGS yields R[j][j] > 0 directly => Q already sign-fixed.
//
// R7 (on top of R6's left-looking 2-panel MGS that killed the spill):
//  (i)  explicit q4 register CSE: R6 counters fit the no-CSE model (DS pipe
//       ~192us: 9 b128/wave/j); load q_j once, use for dot AND update.
//  (ii) qpan XOR swizzle (float4-idx g*16 + (rb^2g)): the apply read was a
//       4-addr/bank-quad conflict (SQ_LDS_BANK_CONFLICT 22.5M). Writer/dot
//       stay 2-way (free); apply drops to 2-way over all 8 quads.
// Both changes preserve FMA order exactly -> absmax must stay 0.09765625.
// ---------------------------------------------------------------------------

static constexpr int BB = 32;  // batch

// -------- DPP 16-lane all-reduce (sum) on the VALU pipe --------------------
template<int CTRL>
__device__ __forceinline__ float dpp_add(float x) {
    int y = __builtin_amdgcn_update_dpp(0, __float_as_int(x), CTRL, 0xF, 0xF, false);
    return x + __int_as_float(y);
}
__device__ __forceinline__ float rowred16(float p) {
    p = dpp_add<0x128>(p);  // row_ror:8
    p = dpp_add<0x124>(p);  // row_ror:4
    p = dpp_add<0x122>(p);  // row_ror:2
    p = dpp_add<0x121>(p);  // row_ror:1
    return p;               // all 16 lanes of the row hold the sum
}

// qpan slot layout (1KB per col j): row r = r16*16 + 4g + e stored at
// float idx j*256 + g*64 + ((r16 ^ 2g) << 2) + e. XOR spreads the apply
// read across all 8 bank-quads; writer/dot groups stay 2-way (free).
__device__ __forceinline__ int qoff(int j, int g, int r16) {
    return j * 256 + g * 64 + ((r16 ^ (2 * g)) << 2);
}

// -------- transpose: in (R, S) row-major -> out (S, R) row-major ----------
__global__ __launch_bounds__(256) void tkern(const float* __restrict__ in,
                                             float* __restrict__ out,
                                             int R, int S) {
    __shared__ float tile[32][33];
    const int tx = threadIdx.x, ty = threadIdx.y;
    const int s0 = blockIdx.x * 32, r0 = blockIdx.y * 32;
    #pragma unroll
    for (int i = ty; i < 32; i += 8) {
        int r = r0 + i, s = s0 + tx;
        tile[i][tx] = (r < R && s < S) ? in[(size_t)r * S + s] : 0.f;
    }
    __syncthreads();
    #pragma unroll
    for (int i = ty; i < 32; i += 8) {
        int s = s0 + i, r = r0 + tx;
        if (s < S && r < R) out[(size_t)s * R + r] = tile[tx][i];
    }
}

// ===========================================================================
// C=64 path: unchanged (register-resident MGS + chunked apply).
// ===========================================================================
template<int C, int CT, int KC>
__device__ __forceinline__ void qr_body(const float* __restrict__ W,
                                        float* __restrict__ XY) {
    constexpr int RT = 16;
    constexpr int TR = C / RT;
    constexpr int THREADS = RT * CT;
    constexpr int QSTR = TR + 4;
    constexpr int XSTR = C + 4;

    const int s  = blockIdx.x;
    const int t  = threadIdx.x;
    const int rb = t & 15;
    const int cb = t >> 4;

    __shared__ float qs[2][RT * QSTR];
    __shared__ float xs[BB * XSTR];
    __shared__ float qc[KC * C];

    float a[TR][4];
    {
        const float* Wp = W + (size_t)s * C * C + (size_t)(rb * TR) * C + cb * 4;
        #pragma unroll
        for (int i = 0; i < TR; ++i) {
            float4 v = *reinterpret_cast<const float4*>(Wp + (size_t)i * C);
            a[i][0] = v.x; a[i][1] = v.y; a[i][2] = v.z; a[i][3] = v.w;
        }
    }
    {
        const float* Xp = XY + (size_t)s * BB * C;
        #pragma unroll
        for (int v = 0; v < (BB * C) / (4 * THREADS); ++v) {
            int idx = 4 * (t + v * THREADS);
            int b = idx / C, k = idx % C;
            float4 x4 = *reinterpret_cast<const float4*>(Xp + idx);
            *reinterpret_cast<float4*>(&xs[b * XSTR + k]) = x4;
        }
    }

    int buf = 0;
    #pragma unroll 1
    for (int j = 0; j < C; ++j) {
        const int cbj = j >> 2, jj = j & 3;
        if (cb == cbj) {
            #pragma unroll
            for (int q = 0; q < 4; ++q) {
                if (q == jj) {
                    float p = 0.f;
                    #pragma unroll
                    for (int i = 0; i < TR; ++i) p += a[i][q] * a[i][q];
                    p = rowred16(p);
                    const float rn = 1.0f / sqrtf(p);
                    #pragma unroll
                    for (int i = 0; i < TR; ++i) a[i][q] *= rn;
                    #pragma unroll
                    for (int i = 0; i < TR; i += 4) {
                        *reinterpret_cast<float4*>(&qs[buf][rb * QSTR + i]) =
                            make_float4(a[i][q], a[i+1][q], a[i+2][q], a[i+3][q]);
                    }
                }
            }
        }
        __syncthreads();
        if (cb * 4 + 3 > j) {
            float qv[TR];
            #pragma unroll
            for (int i = 0; i < TR; i += 4) {
                float4 v = *reinterpret_cast<const float4*>(&qs[buf][rb * QSTR + i]);
                qv[i] = v.x; qv[i+1] = v.y; qv[i+2] = v.z; qv[i+3] = v.w;
            }
            #pragma unroll
            for (int q = 0; q < 4; ++q) {
                if (cb * 4 + q > j) {
                    float p = 0.f;
                    #pragma unroll
                    for (int i = 0; i < TR; ++i) p += a[i][q] * qv[i];
                    p = rowred16(p);
                    #pragma unroll
                    for (int i = 0; i < TR; ++i) a[i][q] -= p * qv[i];
                }
            }
        }
        buf ^= 1;
    }

    const int u  = t % (C / 4);
    const int bp = t / (C / 4);
    float acc[2][4] = {{0,0,0,0},{0,0,0,0}};

    #pragma unroll 1
    for (int ch = 0; ch < C / KC; ++ch) {
        __syncthreads();
        if (cb >= (ch * KC) / 4 && cb < ((ch + 1) * KC) / 4) {
            #pragma unroll
            for (int q = 0; q < 4; ++q) {
                const int kk = cb * 4 + q - ch * KC;
                const int swz = (kk & 7) << 2;
                #pragma unroll
                for (int i = 0; i < TR; i += 4) {
                    const int cout = rb * TR + i;
                    *reinterpret_cast<float4*>(&qc[kk * C + (cout ^ swz)]) =
                        make_float4(a[i][q], a[i+1][q], a[i+2][q], a[i+3][q]);
                }
            }
        }
        __syncthreads();
        #pragma unroll
        for (int kk = 0; kk < KC; kk += 4) {
            const int k = ch * KC + kk;
            float4 x0 = *reinterpret_cast<const float4*>(&xs[(2*bp    ) * XSTR + k]);
            float4 x1 = *reinterpret_cast<const float4*>(&xs[(2*bp + 1) * XSTR + k]);
            #pragma unroll
            for (int m = 0; m < 4; ++m) {
                const int swz = ((kk + m) & 7) << 2;
                float4 qv4 = *reinterpret_cast<const float4*>(&qc[(kk + m) * C + ((4 * u) ^ swz)]);
                const float xa = (&x0.x)[m], xb = (&x1.x)[m];
                acc[0][0] += xa * qv4.x; acc[0][1] += xa * qv4.y;
                acc[0][2] += xa * qv4.z; acc[0][3] += xa * qv4.w;
                acc[1][0] += xb * qv4.x; acc[1][1] += xb * qv4.y;
                acc[1][2] += xb * qv4.z; acc[1][3] += xb * qv4.w;
            }
        }
    }
    {
        float* Yp = XY + (size_t)s * BB * C;
        *reinterpret_cast<float4*>(Yp + (2*bp    ) * C + 4 * u) =
            make_float4(acc[0][0], acc[0][1], acc[0][2], acc[0][3]);
        *reinterpret_cast<float4*>(Yp + (2*bp + 1) * C + 4 * u) =
            make_float4(acc[1][0], acc[1][1], acc[1][2], acc[1][3]);
    }
}

__global__ __launch_bounds__(256) void qr64(const float* __restrict__ W,
                                            float* __restrict__ XY) {
    qr_body<64, 16, 64>(W, XY);
}

// ===========================================================================
// C=256 left-looking 2-panel MGS, 1024 threads, 64-VGPR-budget-sized.
//   rb = t&15: lane's 16 rows = rb*16..rb*16+15
//   cb = t>>4: group owns panel cols {2cb, 2cb+1}
//   qpan[j]: 1KB slot, XOR-swizzled layout via qoff()
//   Y mapping: u=t&63 -> c=4u..4u+3; v=t>>6 -> b=2v,2v+1
// ===========================================================================
__device__ __forceinline__ void panel_mgs(float (&a)[2][16], float (&y0)[4],
                                          float (&y1)[4], float* qpan,
                                          const float* xsb,
                                          int rb, int cb, int u, int v) {
    #pragma unroll 1
    for (int j = 0; j < 128; ++j) {
        if (cb == (j >> 1)) {
            #pragma unroll
            for (int s2 = 0; s2 < 2; ++s2) {
                if (s2 == (j & 1)) {   // static index behind uniform branch
                    float p = 0.f;
                    #pragma unroll
                    for (int i = 0; i < 16; ++i) p += a[s2][i] * a[s2][i];
                    p = rowred16(p);
                    const float rn = 1.0f / sqrtf(p);
                    #pragma unroll
                    for (int i = 0; i < 16; ++i) a[s2][i] *= rn;
                    #pragma unroll
                    for (int g = 0; g < 4; ++g) {
                        *reinterpret_cast<float4*>(&qpan[qoff(j, g, rb)]) =
                            make_float4(a[s2][4*g], a[s2][4*g+1],
                                        a[s2][4*g+2], a[s2][4*g+3]);
                    }
                }
            }
        }
        __syncthreads();
        const bool act1 = (2*cb + 1 > j);
        const bool act0 = (2*cb > j);
        if (act1) {   // row-uniform guard: DPP rows stay converged
            // ---- q_j loaded ONCE into registers (CSE), used by dot+update --
            const float4 q40 = *reinterpret_cast<const float4*>(&qpan[qoff(j, 0, rb)]);
            const float4 q41 = *reinterpret_cast<const float4*>(&qpan[qoff(j, 1, rb)]);
            const float4 q42 = *reinterpret_cast<const float4*>(&qpan[qoff(j, 2, rb)]);
            const float4 q43 = *reinterpret_cast<const float4*>(&qpan[qoff(j, 3, rb)]);
            float p0 = 0.f, p1 = 0.f;
            p0 += a[0][ 0]*q40.x; p1 += a[1][ 0]*q40.x;
            p0 += a[0][ 1]*q40.y; p1 += a[1][ 1]*q40.y;
            p0 += a[0][ 2]*q40.z; p1 += a[1][ 2]*q40.z;
            p0 += a[0][ 3]*q40.w; p1 += a[1][ 3]*q40.w;
            p0 += a[0][ 4]*q41.x; p1 += a[1][ 4]*q41.x;
            p0 += a[0][ 5]*q41.y; p1 += a[1][ 5]*q41.y;
            p0 += a[0][ 6]*q41.z; p1 += a[1][ 6]*q41.z;
            p0 += a[0][ 7]*q41.w; p1 += a[1][ 7]*q41.w;
            p0 += a[0][ 8]*q42.x; p1 += a[1][ 8]*q42.x;
            p0 += a[0][ 9]*q42.y; p1 += a[1][ 9]*q42.y;
            p0 += a[0][10]*q42.z; p1 += a[1][10]*q42.z;
            p0 += a[0][11]*q42.w; p1 += a[1][11]*q42.w;
            p0 += a[0][12]*q43.x; p1 += a[1][12]*q43.x;
            p0 += a[0][13]*q43.y; p1 += a[1][13]*q43.y;
            p0 += a[0][14]*q43.z; p1 += a[1][14]*q43.z;
            p0 += a[0][15]*q43.w; p1 += a[1][15]*q43.w;
            p0 = rowred16(p0); p1 = rowred16(p1);
            if (act0) {
                a[0][ 0] -= p0*q40.x; a[0][ 1] -= p0*q40.y;
                a[0][ 2] -= p0*q40.z; a[0][ 3] -= p0*q40.w;
                a[0][ 4] -= p0*q41.x; a[0][ 5] -= p0*q41.y;
                a[0][ 6] -= p0*q41.z; a[0][ 7] -= p0*q41.w;
                a[0][ 8] -= p0*q42.x; a[0][ 9] -= p0*q42.y;
                a[0][10] -= p0*q42.z; a[0][11] -= p0*q42.w;
                a[0][12] -= p0*q43.x; a[0][13] -= p0*q43.y;
                a[0][14] -= p0*q43.z; a[0][15] -= p0*q43.w;
            }
            a[1][ 0] -= p1*q40.x; a[1][ 1] -= p1*q40.y;
            a[1][ 2] -= p1*q40.z; a[1][ 3] -= p1*q40.w;
            a[1][ 4] -= p1*q41.x; a[1][ 5] -= p1*q41.y;
            a[1][ 6] -= p1*q41.z; a[1][ 7] -= p1*q41.w;
            a[1][ 8] -= p1*q42.x; a[1][ 9] -= p1*q42.y;
            a[1][10] -= p1*q42.z; a[1][11] -= p1*q42.w;
            a[1][12] -= p1*q43.x; a[1][13] -= p1*q43.y;
            a[1][14] -= p1*q43.z; a[1][15] -= p1*q43.w;
        }
        {   // fused rank-1 apply: y += x[b,j] * q_j[c]   (j ascending)
            float4 q4 = *reinterpret_cast<const float4*>(
                &qpan[qoff(j, u & 3, u >> 2)]);
            const float xa = xsb[j*33 + 2*v];
            const float xb = xsb[j*33 + 2*v + 1];
            y0[0] += xa*q4.x; y0[1] += xa*q4.y; y0[2] += xa*q4.z; y0[3] += xa*q4.w;
            y1[0] += xb*q4.x; y1[1] += xb*q4.y; y1[2] += xb*q4.z; y1[3] += xb*q4.w;
        }
    }
}

__global__ __launch_bounds__(1024) void qr256ll(const float* __restrict__ W,
                                                float* __restrict__ XY) {
    __shared__ float qpan[128 * 256];   // 128 KiB: finished q's, 1KB/col slot
    __shared__ float xsb[128 * 33];     // 16.5 KiB: X panel [col][b], pad 33

    const int s  = blockIdx.x;
    const int t  = threadIdx.x;
    const int rb = t & 15;
    const int cb = t >> 4;
    const int u  = t & 63;
    const int v  = t >> 6;

    const float* Wp = W + (size_t)s * 65536;
    float* Xp = XY + (size_t)s * 8192;

    float a[2][16];
    float y0[4] = {0,0,0,0};
    float y1[4] = {0,0,0,0};

    // ---- panel 0: load W cols [0,128) + stage X cols [0,128) ----
    #pragma unroll
    for (int i = 0; i < 16; ++i) {
        float2 w2 = *reinterpret_cast<const float2*>(
            Wp + (size_t)(rb*16 + i) * 256 + 2*cb);
        a[0][i] = w2.x; a[1][i] = w2.y;
    }
    {
        const int tj = t & 127, tb = t >> 7;
        #pragma unroll
        for (int d = 0; d < 4; ++d)
            xsb[tj*33 + 4*tb + d] = Xp[(4*tb + d)*256 + tj];
    }
    __syncthreads();

    panel_mgs(a, y0, y1, qpan, xsb, rb, cb, u, v);

    // ---- glue: reload regs with W cols [128,256), restage X, cross-pass ----
    __syncthreads();   // panel-0 consumers done before xsb is overwritten
    #pragma unroll
    for (int i = 0; i < 16; ++i) {
        float2 w2 = *reinterpret_cast<const float2*>(
            Wp + (size_t)(rb*16 + i) * 256 + 128 + 2*cb);
        a[0][i] = w2.x; a[1][i] = w2.y;
    }
    {
        const int tj = t & 127, tb = t >> 7;
        #pragma unroll
        for (int d = 0; d < 4; ++d)
            xsb[tj*33 + 4*tb + d] = Xp[(4*tb + d)*256 + 128 + tj];
    }
    // cross-pass: orthogonalize both register cols vs Q0 (barrier-free;
    // qpan is read-only here, xsb writes above touch a disjoint region)
    #pragma unroll 1
    for (int k = 0; k < 128; ++k) {
        const float4 q40 = *reinterpret_cast<const float4*>(&qpan[qoff(k, 0, rb)]);
        const float4 q41 = *reinterpret_cast<const float4*>(&qpan[qoff(k, 1, rb)]);
        const float4 q42 = *reinterpret_cast<const float4*>(&qpan[qoff(k, 2, rb)]);
        const float4 q43 = *reinterpret_cast<const float4*>(&qpan[qoff(k, 3, rb)]);
        float p0 = 0.f, p1 = 0.f;
        p0 += a[0][ 0]*q40.x; p1 += a[1][ 0]*q40.x;
        p0 += a[0][ 1]*q40.y; p1 += a[1][ 1]*q40.y;
        p0 += a[0][ 2]*q40.z; p1 += a[1][ 2]*q40.z;
        p0 += a[0][ 3]*q40.w; p1 += a[1][ 3]*q40.w;
        p0 += a[0][ 4]*q41.x; p1 += a[1][ 4]*q41.x;
        p0 += a[0][ 5]*q41.y; p1 += a[1][ 5]*q41.y;
        p0 += a[0][ 6]*q41.z; p1 += a[1][ 6]*q41.z;
        p0 += a[0][ 7]*q41.w; p1 += a[1][ 7]*q41.w;
        p0 += a[0][ 8]*q42.x; p1 += a[1][ 8]*q42.x;
        p0 += a[0][ 9]*q42.y; p1 += a[1][ 9]*q42.y;
        p0 += a[0][10]*q42.z; p1 += a[1][10]*q42.z;
        p0 += a[0][11]*q42.w; p1 += a[1][11]*q42.w;
        p0 += a[0][12]*q43.x; p1 += a[1][12]*q43.x;
        p0 += a[0][13]*q43.y; p1 += a[1][13]*q43.y;
        p0 += a[0][14]*q43.z; p1 += a[1][14]*q43.z;
        p0 += a[0][15]*q43.w; p1 += a[1][15]*q43.w;
        p0 = rowred16(p0); p1 = rowred16(p1);
        a[0][ 0] -= p0*q40.x; a[0][ 1] -= p0*q40.y;
        a[0][ 2] -= p0*q40.z; a[0][ 3] -= p0*q40.w;
        a[0][ 4] -= p0*q41.x; a[0][ 5] -= p0*q41.y;
        a[0][ 6] -= p0*q41.z; a[0][ 7] -= p0*q41.w;
        a[0][ 8] -= p0*q42.x; a[0][ 9] -= p0*q42.y;
        a[0][10] -= p0*q42.z; a[0][11] -= p0*q42.w;
        a[0][12] -= p0*q43.x; a[0][13] -= p0*q43.y;
        a[0][14] -= p0*q43.z; a[0][15] -= p0*q43.w;
        a[1][ 0] -= p1*q40.x; a[1][ 1] -= p1*q40.y;
        a[1][ 2] -= p1*q40.z; a[1][ 3] -= p1*q40.w;
        a[1][ 4] -= p1*q41.x; a[1][ 5] -= p1*q41.y;
        a[1][ 6] -= p1*q41.z; a[1][ 7] -= p1*q41.w;
        a[1][ 8] -= p1*q42.x; a[1][ 9] -= p1*q42.y;
        a[1][10] -= p1*q42.z; a[1][11] -= p1*q42.w;
        a[1][12] -= p1*q43.x; a[1][13] -= p1*q43.y;
        a[1][14] -= p1*q43.z; a[1][15] -= p1*q43.w;
    }
    __syncthreads();   // xsb staged + cross-pass complete everywhere

    // ---- panel 1 (qpan slots reused; Q0 no longer needed) ----
    panel_mgs(a, y0, y1, qpan, xsb, rb, cb, u, v);

    // ---- write Y in place over X (coalesced float4) ----
    *reinterpret_cast<float4*>(Xp + (size_t)(2*v    )*256 + 4*u) =
        make_float4(y0[0], y0[1], y0[2], y0[3]);
    *reinterpret_cast<float4*>(Xp + (size_t)(2*v + 1)*256 + 4*u) =
        make_float4(y1[0], y1[1], y1[2], y1[3]);
}

extern "C" void kernel_launch(void* const* d_in, const int* in_sizes, int n_in,
                              void* d_out, int out_size, void* d_ws, size_t ws_size,
                              hipStream_t stream) {
    (void)in_sizes; (void)n_in; (void)out_size; (void)ws_size;
    const float* x0 = (const float*)d_in[0];  // (32, 64, 784)
    const float* x1 = (const float*)d_in[1];  // (32, 256, 196)
    const float* W0 = (const float*)d_in[2];  // (784, 64, 64)
    const float* W1 = (const float*)d_in[3];  // (196, 256, 256)
    float* y0  = (float*)d_out;               // (32, 64, 784) flat
    float* y1  = y0 + 1605632;                // (32, 256, 196) flat
    float* xt0 = (float*)d_ws;                // (784, 32*64)
    float* xt1 = xt0 + 1605632;               // (196, 32*256)

    dim3 tb(32, 8);
    // x (B*C, S) -> xt (S, B*C)
    tkern<<<dim3(25,  64), tb, 0, stream>>>(x0, xt0, 2048, 784);
    tkern<<<dim3(7,  256), tb, 0, stream>>>(x1, xt1, 8192, 196);
    // fused QR + apply (Y overwrites xt in place)
    qr64   <<<784,  256, 0, stream>>>(W0, xt0);
    qr256ll<<<196, 1024, 0, stream>>>(W1, xt1);
    // xt (S, B*C) -> y (B*C, S)
    tkern<<<dim3(64,  25), tb, 0, stream>>>(xt0, y0, 784, 2048);
    tkern<<<dim3(256,  7), tb, 0, stream>>>(xt1, y1, 196, 8192);
}